// Round 1
// baseline (1194.166 us; speedup 1.0000x reference)
//
#include <hip/hip_runtime.h>
#include <hip/hip_bf16.h>
#include <cstdint>
#include <cstddef>

// ---------------------------------------------------------------------------
// MultiValGCN: out = log_softmax( adjcat @ relu(adjcat @ (x W1)cat + b1) W2cat + b2 )
// adjcat: [8192 x 24576] view of adj[3][8192][8192] (order concatenated on K).
// All GEMMs in bf16 MFMA (16x16x32), f32 accumulate. adj converted f32->bf16
// on the fly in the staging path (cheaper than a pre-conversion pass).
// ---------------------------------------------------------------------------

typedef __bf16 bf16_t;
typedef __bf16 bf16x8 __attribute__((ext_vector_type(8)));
typedef __bf16 bf16x4 __attribute__((ext_vector_type(4)));
typedef float  f32x4  __attribute__((ext_vector_type(4)));

#define NROWS 8192
#define DIN   512
#define DHID  1024
#define DOUT  64
#define ORD   3
#define KTOT  24576   // ORD*NROWS

#define GLDS(g, l) __builtin_amdgcn_global_load_lds( \
    (__attribute__((address_space(1))) void*)(g),    \
    (__attribute__((address_space(3))) void*)(l), 16, 0, 0)

// ---------------- x: f32 -> bf16 ----------------
__global__ void k_cvt_x(const float* __restrict__ x, bf16_t* __restrict__ xb) {
  int i = blockIdx.x * blockDim.x + threadIdx.x;            // one per 8 elems
  const float4* p = reinterpret_cast<const float4*>(x) + (size_t)i * 2;
  float4 v0 = p[0], v1 = p[1];
  bf16x8 o;
  o[0]=(bf16_t)v0.x; o[1]=(bf16_t)v0.y; o[2]=(bf16_t)v0.z; o[3]=(bf16_t)v0.w;
  o[4]=(bf16_t)v1.x; o[5]=(bf16_t)v1.y; o[6]=(bf16_t)v1.z; o[7]=(bf16_t)v1.w;
  *reinterpret_cast<bf16x8*>(xb + (size_t)i * 8) = o;
}

// ---------------- W transpose + cvt: src f32 [R][C] -> dst bf16 [C][R], per order z
__global__ void k_transpose_cvt(const float* __restrict__ src, bf16_t* __restrict__ dst,
                                int R, int C) {
  __shared__ float tile[64][65];
  int ord = blockIdx.z;
  src += (size_t)ord * R * C;
  dst += (size_t)ord * R * C;
  int c0 = blockIdx.x * 64, r0 = blockIdx.y * 64;
  for (int i = 0; i < 16; ++i) {
    int idx = i * 256 + threadIdx.x;
    int r = idx >> 6, c = idx & 63;
    tile[r][c] = src[(size_t)(r0 + r) * C + c0 + c];
  }
  __syncthreads();
  for (int i = 0; i < 16; ++i) {
    int idx = i * 256 + threadIdx.x;
    int cc = idx >> 6, rr = idx & 63;
    dst[(size_t)(c0 + cc) * R + r0 + rr] = (bf16_t)tile[rr][cc];
  }
}

// ---------------- K1: xw1T[o][ord*8192+n] = sum_i x(n,i) W1[ord](i,o)  (bf16)
__global__ __launch_bounds__(256) void k_gemm_xw1(
    const bf16_t* __restrict__ xb,    // [8192][512]
    const bf16_t* __restrict__ w1t,   // [3][1024][512]
    bf16_t* __restrict__ xw1t)        // [1024][24576]
{
  __shared__ bf16_t As[128 * 64];
  __shared__ bf16_t Bs[128 * 64];
  int ntile = blockIdx.x, mtile = blockIdx.y, ord = blockIdx.z;
  int tid = threadIdx.x, lane = tid & 63, wid = tid >> 6;
  int wm = wid >> 1, wn = wid & 1;
  f32x4 acc[4][4] = {};
  const bf16_t* w1o = w1t + (size_t)ord * DHID * DIN;
  for (int kt = 0; kt < DIN; kt += 64) {
    for (int j = 0; j < 4; ++j) {           // A: x rows, 16 KB
      int q = wid * 4 + j;
      int row = q * 8 + (lane >> 3);
      const bf16_t* g = xb + (size_t)(mtile * 128 + row) * DIN + kt + (lane & 7) * 8;
      GLDS(g, &As[q * 512]);
    }
    for (int j = 0; j < 4; ++j) {           // B: W1T rows (o), 16 KB
      int q = wid * 4 + j;
      int row = q * 8 + (lane >> 3);
      const bf16_t* g = w1o + (size_t)(ntile * 128 + row) * DIN + kt + (lane & 7) * 8;
      GLDS(g, &Bs[q * 512]);
    }
    __syncthreads();
    for (int ks = 0; ks < 2; ++ks) {
      int ko = ks * 32 + (lane >> 4) * 8;
      bf16x8 a[4], b[4];
      for (int f = 0; f < 4; ++f)
        a[f] = *reinterpret_cast<const bf16x8*>(&As[(wm * 64 + f * 16 + (lane & 15)) * 64 + ko]);
      for (int f = 0; f < 4; ++f)
        b[f] = *reinterpret_cast<const bf16x8*>(&Bs[(wn * 64 + f * 16 + (lane & 15)) * 64 + ko]);
      for (int fm = 0; fm < 4; ++fm)
        for (int fn = 0; fn < 4; ++fn)
          acc[fm][fn] = __builtin_amdgcn_mfma_f32_16x16x32_bf16(a[fm], b[fn], acc[fm][fn], 0, 0, 0);
    }
    __syncthreads();
  }
  // transposed epilogue: lane's 4 regs are 4 consecutive n at fixed o -> 8B store
  for (int fm = 0; fm < 4; ++fm)
    for (int fn = 0; fn < 4; ++fn) {
      int o  = ntile * 128 + wn * 64 + fn * 16 + (lane & 15);
      int n0 = mtile * 128 + wm * 64 + fm * 16 + ((lane >> 4) << 2);
      bf16x4 v;
      v[0] = (bf16_t)acc[fm][fn][0]; v[1] = (bf16_t)acc[fm][fn][1];
      v[2] = (bf16_t)acc[fm][fn][2]; v[3] = (bf16_t)acc[fm][fn][3];
      *reinterpret_cast<bf16x4*>(&xw1t[(size_t)o * KTOT + ord * NROWS + n0]) = v;
    }
}

// ---------------- K2: h = relu(adjcat @ xw1 + b1), bf16 out. M=8192 N=1024 K=24576
__global__ __launch_bounds__(256) void k_gemm_h(
    const float* __restrict__ adj,     // [3][8192][8192] f32
    const bf16_t* __restrict__ xw1t,   // [1024][24576]
    const float* __restrict__ b1,      // [1024]
    bf16_t* __restrict__ h)            // [8192][1024]
{
  __shared__ bf16_t As[128 * 64];
  __shared__ bf16_t Bs[128 * 64];
  int ntile = blockIdx.x, mtile = blockIdx.y;
  int tid = threadIdx.x, lane = tid & 63, wid = tid >> 6;
  int wm = wid >> 1, wn = wid & 1;
  f32x4 acc[4][4] = {};
  for (int kt = 0; kt < KTOT / 64; ++kt) {
    int kk0 = kt * 64;
    int ord = kk0 >> 13;
    int mcol = kk0 & 8191;
    // B: xw1T rows (o), bf16, direct-to-LDS
    for (int j = 0; j < 4; ++j) {
      int q = wid * 4 + j;
      int row = q * 8 + (lane >> 3);
      const bf16_t* g = xw1t + (size_t)(ntile * 128 + row) * KTOT + kk0 + (lane & 7) * 8;
      GLDS(g, &Bs[q * 512]);
    }
    // A: adj f32 -> bf16, reg-staged
    const float* abase = adj + (size_t)ord * NROWS * NROWS + (size_t)(mtile * 128) * NROWS + mcol;
    bf16x8 st[4]; int mrow[4], kb[4];
    for (int i = 0; i < 4; ++i) {
      int c = i * 256 + tid;
      mrow[i] = c >> 3; kb[i] = c & 7;
      const float4* p = reinterpret_cast<const float4*>(abase + (size_t)mrow[i] * NROWS + kb[i] * 8);
      float4 v0 = p[0], v1 = p[1];
      bf16x8 o;
      o[0]=(bf16_t)v0.x; o[1]=(bf16_t)v0.y; o[2]=(bf16_t)v0.z; o[3]=(bf16_t)v0.w;
      o[4]=(bf16_t)v1.x; o[5]=(bf16_t)v1.y; o[6]=(bf16_t)v1.z; o[7]=(bf16_t)v1.w;
      st[i] = o;
    }
    for (int i = 0; i < 4; ++i)
      *reinterpret_cast<bf16x8*>(&As[mrow[i] * 64 + kb[i] * 8]) = st[i];
    __syncthreads();
    for (int ks = 0; ks < 2; ++ks) {
      int ko = ks * 32 + (lane >> 4) * 8;
      bf16x8 a[4], b[4];
      for (int f = 0; f < 4; ++f)
        a[f] = *reinterpret_cast<const bf16x8*>(&As[(wm * 64 + f * 16 + (lane & 15)) * 64 + ko]);
      for (int f = 0; f < 4; ++f)
        b[f] = *reinterpret_cast<const bf16x8*>(&Bs[(wn * 64 + f * 16 + (lane & 15)) * 64 + ko]);
      for (int fm = 0; fm < 4; ++fm)
        for (int fn = 0; fn < 4; ++fn)
          acc[fm][fn] = __builtin_amdgcn_mfma_f32_16x16x32_bf16(a[fm], b[fn], acc[fm][fn], 0, 0, 0);
    }
    __syncthreads();
  }
  for (int fm = 0; fm < 4; ++fm)
    for (int fn = 0; fn < 4; ++fn) {
      int o  = ntile * 128 + wn * 64 + fn * 16 + (lane & 15);
      float bias = b1[o];
      int n0 = mtile * 128 + wm * 64 + fm * 16 + ((lane >> 4) << 2);
      for (int j = 0; j < 4; ++j) {
        float v = acc[fm][fn][j] + bias;
        v = v > 0.0f ? v : 0.0f;
        h[(size_t)(n0 + j) * DHID + o] = (bf16_t)v;
      }
    }
}

// ---------------- K3: xw2T[o2][ord*8192+n] = sum_o h(n,o) W2[ord](o,o2)
__global__ __launch_bounds__(256) void k_gemm_xw2(
    const bf16_t* __restrict__ h,     // [8192][1024]
    const bf16_t* __restrict__ w2t,   // [3][64][1024]
    bf16_t* __restrict__ xw2t)        // [64][24576]
{
  __shared__ bf16_t As[128 * 64];
  __shared__ bf16_t Bs[64 * 64];
  int mtile = blockIdx.x, ord = blockIdx.y;
  int tid = threadIdx.x, lane = tid & 63, wid = tid >> 6;
  int wm = wid >> 1, wn = wid & 1;
  f32x4 acc[4][2] = {};
  const bf16_t* w2o = w2t + (size_t)ord * DOUT * DHID;
  for (int kt = 0; kt < DHID; kt += 64) {
    for (int j = 0; j < 4; ++j) {           // A: h rows
      int q = wid * 4 + j;
      int row = q * 8 + (lane >> 3);
      const bf16_t* g = h + (size_t)(mtile * 128 + row) * DHID + kt + (lane & 7) * 8;
      GLDS(g, &As[q * 512]);
    }
    for (int j = 0; j < 2; ++j) {           // B: W2T rows (o2), 8 KB
      int q = wid * 2 + j;
      int row = q * 8 + (lane >> 3);
      const bf16_t* g = w2o + (size_t)row * DHID + kt + (lane & 7) * 8;
      GLDS(g, &Bs[q * 512]);
    }
    __syncthreads();
    for (int ks = 0; ks < 2; ++ks) {
      int ko = ks * 32 + (lane >> 4) * 8;
      bf16x8 a[4], b[2];
      for (int f = 0; f < 4; ++f)
        a[f] = *reinterpret_cast<const bf16x8*>(&As[(wm * 64 + f * 16 + (lane & 15)) * 64 + ko]);
      for (int f = 0; f < 2; ++f)
        b[f] = *reinterpret_cast<const bf16x8*>(&Bs[(wn * 32 + f * 16 + (lane & 15)) * 64 + ko]);
      for (int fm = 0; fm < 4; ++fm)
        for (int fn = 0; fn < 2; ++fn)
          acc[fm][fn] = __builtin_amdgcn_mfma_f32_16x16x32_bf16(a[fm], b[fn], acc[fm][fn], 0, 0, 0);
    }
    __syncthreads();
  }
  for (int fm = 0; fm < 4; ++fm)
    for (int fn = 0; fn < 2; ++fn) {
      int o2 = wn * 32 + fn * 16 + (lane & 15);
      int n0 = mtile * 128 + wm * 64 + fm * 16 + ((lane >> 4) << 2);
      bf16x4 v;
      v[0] = (bf16_t)acc[fm][fn][0]; v[1] = (bf16_t)acc[fm][fn][1];
      v[2] = (bf16_t)acc[fm][fn][2]; v[3] = (bf16_t)acc[fm][fn][3];
      *reinterpret_cast<bf16x4*>(&xw2t[(size_t)o2 * KTOT + ord * NROWS + n0]) = v;
    }
}

// ---------------- K4a: partial z = adjcat @ xw2, K split 4 ways
__global__ __launch_bounds__(256) void k_gemm_out(
    const float* __restrict__ adj,
    const bf16_t* __restrict__ xw2t,   // [64][24576]
    float* __restrict__ part)          // [4][8192][64]
{
  __shared__ bf16_t As[128 * 64];
  __shared__ bf16_t Bs[64 * 64];
  int mtile = blockIdx.x, ksp = blockIdx.y;
  int tid = threadIdx.x, lane = tid & 63, wid = tid >> 6;
  int wm = wid >> 1, wn = wid & 1;
  f32x4 acc[4][2] = {};
  for (int kt = ksp * 96; kt < ksp * 96 + 96; ++kt) {
    int kk0 = kt * 64;
    int ord = kk0 >> 13;
    int mcol = kk0 & 8191;
    for (int j = 0; j < 2; ++j) {           // B: xw2T rows (o2)
      int q = wid * 2 + j;
      int row = q * 8 + (lane >> 3);
      const bf16_t* g = xw2t + (size_t)row * KTOT + kk0 + (lane & 7) * 8;
      GLDS(g, &Bs[q * 512]);
    }
    const float* abase = adj + (size_t)ord * NROWS * NROWS + (size_t)(mtile * 128) * NROWS + mcol;
    bf16x8 st[4]; int mrow[4], kb[4];
    for (int i = 0; i < 4; ++i) {
      int c = i * 256 + tid;
      mrow[i] = c >> 3; kb[i] = c & 7;
      const float4* p = reinterpret_cast<const float4*>(abase + (size_t)mrow[i] * NROWS + kb[i] * 8);
      float4 v0 = p[0], v1 = p[1];
      bf16x8 o;
      o[0]=(bf16_t)v0.x; o[1]=(bf16_t)v0.y; o[2]=(bf16_t)v0.z; o[3]=(bf16_t)v0.w;
      o[4]=(bf16_t)v1.x; o[5]=(bf16_t)v1.y; o[6]=(bf16_t)v1.z; o[7]=(bf16_t)v1.w;
      st[i] = o;
    }
    for (int i = 0; i < 4; ++i)
      *reinterpret_cast<bf16x8*>(&As[mrow[i] * 64 + kb[i] * 8]) = st[i];
    __syncthreads();
    for (int ks = 0; ks < 2; ++ks) {
      int ko = ks * 32 + (lane >> 4) * 8;
      bf16x8 a[4], b[2];
      for (int f = 0; f < 4; ++f)
        a[f] = *reinterpret_cast<const bf16x8*>(&As[(wm * 64 + f * 16 + (lane & 15)) * 64 + ko]);
      for (int f = 0; f < 2; ++f)
        b[f] = *reinterpret_cast<const bf16x8*>(&Bs[(wn * 32 + f * 16 + (lane & 15)) * 64 + ko]);
      for (int fm = 0; fm < 4; ++fm)
        for (int fn = 0; fn < 2; ++fn)
          acc[fm][fn] = __builtin_amdgcn_mfma_f32_16x16x32_bf16(a[fm], b[fn], acc[fm][fn], 0, 0, 0);
    }
    __syncthreads();
  }
  float* pout = part + (size_t)ksp * NROWS * DOUT;
  for (int fm = 0; fm < 4; ++fm)
    for (int fn = 0; fn < 2; ++fn) {
      int o2 = wn * 32 + fn * 16 + (lane & 15);
      int n0 = mtile * 128 + wm * 64 + fm * 16 + ((lane >> 4) << 2);
      for (int j = 0; j < 4; ++j)
        pout[(size_t)(n0 + j) * DOUT + o2] = acc[fm][fn][j];
    }
}

// ---------------- K4b: sum partials + b2, row log_softmax ----------------
__global__ void k_logsoftmax(const float* __restrict__ part, const float* __restrict__ b2,
                             float* __restrict__ out) {
  int wid = threadIdx.x >> 6, lane = threadIdx.x & 63;
  int n = blockIdx.x * 4 + wid;
  size_t s = (size_t)NROWS * DOUT;
  float v = part[(size_t)n * DOUT + lane] + part[s + (size_t)n * DOUT + lane]
          + part[2 * s + (size_t)n * DOUT + lane] + part[3 * s + (size_t)n * DOUT + lane]
          + b2[lane];
  float mx = v;
  for (int d = 32; d; d >>= 1) mx = fmaxf(mx, __shfl_xor(mx, d));
  float e = expf(v - mx);
  float sum = e;
  for (int d = 32; d; d >>= 1) sum += __shfl_xor(sum, d);
  out[(size_t)n * DOUT + lane] = (v - mx) - logf(sum);
}

// ---------------------------------------------------------------------------
extern "C" void kernel_launch(void* const* d_in, const int* in_sizes, int n_in,
                              void* d_out, int out_size, void* d_ws, size_t ws_size,
                              hipStream_t stream) {
  const float* x   = (const float*)d_in[0];
  const float* adj = (const float*)d_in[1];
  const float* W1  = (const float*)d_in[2];
  const float* b1  = (const float*)d_in[3];
  const float* W2  = (const float*)d_in[4];
  const float* b2  = (const float*)d_in[5];
  float* out = (float*)d_out;
  char* ws = (char*)d_ws;

  bf16_t* xb   = (bf16_t*)(ws + 0);          //  8 MB  [8192][512]
  bf16_t* w1t  = (bf16_t*)(ws + 8388608);    //  3 MB  [3][1024][512]
  bf16_t* w2t  = (bf16_t*)(ws + 11534336);   //  384K  [3][64][1024]
  bf16_t* xw1t = (bf16_t*)(ws + 11927552);   // 48 MB  [1024][24576]
  bf16_t* h    = (bf16_t*)(ws + 62259200);   // 16 MB  [8192][1024]
  bf16_t* xw2t = (bf16_t*)(ws + 79036416);   //  3 MB  [64][24576]
  float*  part = (float*)(ws + 82182144);    //  8 MB  [4][8192][64]

  k_cvt_x<<<2048, 256, 0, stream>>>(x, xb);
  k_transpose_cvt<<<dim3(16, 8, 3), 256, 0, stream>>>(W1, w1t, DIN, DHID);
  k_transpose_cvt<<<dim3(1, 16, 3), 256, 0, stream>>>(W2, w2t, DHID, DOUT);
  k_gemm_xw1<<<dim3(8, 64, 3), 256, 0, stream>>>(xb, w1t, xw1t);
  k_gemm_h<<<dim3(8, 64), 256, 0, stream>>>(adj, xw1t, b1, h);
  k_gemm_xw2<<<dim3(64, 3), 256, 0, stream>>>(h, w2t, xw2t);
  k_gemm_out<<<dim3(64, 4), 256, 0, stream>>>(adj, xw2t, part);
  k_logsoftmax<<<2048, 256, 0, stream>>>(part, b2, out);
}

// Round 2
// 981.999 us; speedup vs baseline: 1.2161x; 1.2161x over previous
//
#include <hip/hip_runtime.h>
#include <hip/hip_bf16.h>
#include <cstdint>
#include <cstddef>

// ---------------------------------------------------------------------------
// MultiValGCN: out = log_softmax( adjcat @ relu(adjcat @ (x W1)cat + b1) W2cat + b2 )
// adjcat: [8192 x 24576] view of adj[3][8192][8192] (order concatenated on K).
// bf16 MFMA (16x16x32), f32 accumulate, adj converted f32->bf16 on the fly.
// Round 2: T2 XOR-swizzle on LDS tiles (16-way -> 2-way bank conflicts) and
// XCD-grouped block decode in k_gemm_h (adj panel L2 reuse across ntile-sharers).
// ---------------------------------------------------------------------------

typedef __bf16 bf16_t;
typedef __bf16 bf16x8 __attribute__((ext_vector_type(8)));
typedef __bf16 bf16x4 __attribute__((ext_vector_type(4)));
typedef float  f32x4  __attribute__((ext_vector_type(4)));

#define NROWS 8192
#define DIN   512
#define DHID  1024
#define DOUT  64
#define ORD   3
#define KTOT  24576   // ORD*NROWS

#define GLDS(g, l) __builtin_amdgcn_global_load_lds( \
    (__attribute__((address_space(1))) void*)(g),    \
    (__attribute__((address_space(3))) void*)(l), 16, 0, 0)

// LDS tile layout: [rows][8 slots of 8 bf16]; physical slot = logical ^ (row&7).
// GLDS writes linearly (lane -> slot lane&7 of row lane>>3 within its q-group),
// so the GLOBAL source reads slot (lane&7)^(lane>>3) instead (rule #21).

// ---------------- x: f32 -> bf16 ----------------
__global__ void k_cvt_x(const float* __restrict__ x, bf16_t* __restrict__ xb) {
  int i = blockIdx.x * blockDim.x + threadIdx.x;            // one per 8 elems
  const float4* p = reinterpret_cast<const float4*>(x) + (size_t)i * 2;
  float4 v0 = p[0], v1 = p[1];
  bf16x8 o;
  o[0]=(bf16_t)v0.x; o[1]=(bf16_t)v0.y; o[2]=(bf16_t)v0.z; o[3]=(bf16_t)v0.w;
  o[4]=(bf16_t)v1.x; o[5]=(bf16_t)v1.y; o[6]=(bf16_t)v1.z; o[7]=(bf16_t)v1.w;
  *reinterpret_cast<bf16x8*>(xb + (size_t)i * 8) = o;
}

// ---------------- W transpose + cvt: src f32 [R][C] -> dst bf16 [C][R], per order z
__global__ void k_transpose_cvt(const float* __restrict__ src, bf16_t* __restrict__ dst,
                                int R, int C) {
  __shared__ float tile[64][65];
  int ord = blockIdx.z;
  src += (size_t)ord * R * C;
  dst += (size_t)ord * R * C;
  int c0 = blockIdx.x * 64, r0 = blockIdx.y * 64;
  for (int i = 0; i < 16; ++i) {
    int idx = i * 256 + threadIdx.x;
    int r = idx >> 6, c = idx & 63;
    tile[r][c] = src[(size_t)(r0 + r) * C + c0 + c];
  }
  __syncthreads();
  for (int i = 0; i < 16; ++i) {
    int idx = i * 256 + threadIdx.x;
    int cc = idx >> 6, rr = idx & 63;
    dst[(size_t)(c0 + cc) * R + r0 + rr] = (bf16_t)tile[rr][cc];
  }
}

// ---------------- K1: xw1T[o][ord*8192+n] = sum_i x(n,i) W1[ord](i,o)  (bf16)
__global__ __launch_bounds__(256) void k_gemm_xw1(
    const bf16_t* __restrict__ xb,    // [8192][512]
    const bf16_t* __restrict__ w1t,   // [3][1024][512]
    bf16_t* __restrict__ xw1t)        // [1024][24576]
{
  __shared__ bf16_t As[128 * 64];
  __shared__ bf16_t Bs[128 * 64];
  int ntile = blockIdx.x, mtile = blockIdx.y, ord = blockIdx.z;
  int tid = threadIdx.x, lane = tid & 63, wid = tid >> 6;
  int wm = wid >> 1, wn = wid & 1;
  int sl = (lane & 7) ^ (lane >> 3);              // pre-swizzled source slot
  f32x4 acc[4][4] = {};
  const bf16_t* w1o = w1t + (size_t)ord * DHID * DIN;
  for (int kt = 0; kt < DIN; kt += 64) {
    for (int j = 0; j < 4; ++j) {           // A: x rows, 16 KB
      int q = wid * 4 + j;
      int row = q * 8 + (lane >> 3);
      const bf16_t* g = xb + (size_t)(mtile * 128 + row) * DIN + kt + sl * 8;
      GLDS(g, &As[q * 512]);
    }
    for (int j = 0; j < 4; ++j) {           // B: W1T rows (o), 16 KB
      int q = wid * 4 + j;
      int row = q * 8 + (lane >> 3);
      const bf16_t* g = w1o + (size_t)(ntile * 128 + row) * DIN + kt + sl * 8;
      GLDS(g, &Bs[q * 512]);
    }
    __syncthreads();
    for (int ks = 0; ks < 2; ++ks) {
      int lsl = (ks << 2) + (lane >> 4);    // logical slot
      int psl = lsl ^ (lane & 7);           // physical (row&7 == lane&7)
      bf16x8 a[4], b[4];
      for (int f = 0; f < 4; ++f)
        a[f] = *reinterpret_cast<const bf16x8*>(&As[(wm * 64 + f * 16 + (lane & 15)) * 64 + psl * 8]);
      for (int f = 0; f < 4; ++f)
        b[f] = *reinterpret_cast<const bf16x8*>(&Bs[(wn * 64 + f * 16 + (lane & 15)) * 64 + psl * 8]);
      for (int fm = 0; fm < 4; ++fm)
        for (int fn = 0; fn < 4; ++fn)
          acc[fm][fn] = __builtin_amdgcn_mfma_f32_16x16x32_bf16(a[fm], b[fn], acc[fm][fn], 0, 0, 0);
    }
    __syncthreads();
  }
  // transposed epilogue: lane's 4 regs are 4 consecutive n at fixed o -> 8B store
  for (int fm = 0; fm < 4; ++fm)
    for (int fn = 0; fn < 4; ++fn) {
      int o  = ntile * 128 + wn * 64 + fn * 16 + (lane & 15);
      int n0 = mtile * 128 + wm * 64 + fm * 16 + ((lane >> 4) << 2);
      bf16x4 v;
      v[0] = (bf16_t)acc[fm][fn][0]; v[1] = (bf16_t)acc[fm][fn][1];
      v[2] = (bf16_t)acc[fm][fn][2]; v[3] = (bf16_t)acc[fm][fn][3];
      *reinterpret_cast<bf16x4*>(&xw1t[(size_t)o * KTOT + ord * NROWS + n0]) = v;
    }
}

// ---------------- K2: h = relu(adjcat @ xw1 + b1), bf16 out. M=8192 N=1024 K=24576
__global__ __launch_bounds__(256) void k_gemm_h(
    const float* __restrict__ adj,     // [3][8192][8192] f32
    const bf16_t* __restrict__ xw1t,   // [1024][24576]
    const float* __restrict__ b1,      // [1024]
    bf16_t* __restrict__ h)            // [8192][1024]
{
  __shared__ bf16_t As[128 * 64];
  __shared__ bf16_t Bs[128 * 64];
  // XCD-grouped decode: blocks d = xcd + 8*(mloc*8 + ntile).  The 8 ntile
  // sharers of one adj panel are consecutive on ONE XCD -> L2 reuse.
  int d = blockIdx.x;
  int xcd = d & 7;
  int idx = d >> 3;
  int mtile = xcd * 8 + (idx >> 3);
  int ntile = idx & 7;
  int tid = threadIdx.x, lane = tid & 63, wid = tid >> 6;
  int wm = wid >> 1, wn = wid & 1;
  int sl = (lane & 7) ^ (lane >> 3);
  f32x4 acc[4][4] = {};
  for (int kt = 0; kt < KTOT / 64; ++kt) {
    int kk0 = kt * 64;
    int ord = kk0 >> 13;
    int mcol = kk0 & 8191;
    // B: xw1T rows (o), bf16, direct-to-LDS, pre-swizzled source
    for (int j = 0; j < 4; ++j) {
      int q = wid * 4 + j;
      int row = q * 8 + (lane >> 3);
      const bf16_t* g = xw1t + (size_t)(ntile * 128 + row) * KTOT + kk0 + sl * 8;
      GLDS(g, &Bs[q * 512]);
    }
    // A: adj f32 -> bf16, reg-staged, swizzled ds_write
    const float* abase = adj + (size_t)ord * NROWS * NROWS + (size_t)(mtile * 128) * NROWS + mcol;
    bf16x8 st[4]; int mrow[4], kb[4];
    for (int i = 0; i < 4; ++i) {
      int c = i * 256 + tid;
      mrow[i] = c >> 3; kb[i] = c & 7;
      const float4* p = reinterpret_cast<const float4*>(abase + (size_t)mrow[i] * NROWS + kb[i] * 8);
      float4 v0 = p[0], v1 = p[1];
      bf16x8 o;
      o[0]=(bf16_t)v0.x; o[1]=(bf16_t)v0.y; o[2]=(bf16_t)v0.z; o[3]=(bf16_t)v0.w;
      o[4]=(bf16_t)v1.x; o[5]=(bf16_t)v1.y; o[6]=(bf16_t)v1.z; o[7]=(bf16_t)v1.w;
      st[i] = o;
    }
    for (int i = 0; i < 4; ++i)
      *reinterpret_cast<bf16x8*>(&As[mrow[i] * 64 + (kb[i] ^ (mrow[i] & 7)) * 8]) = st[i];
    __syncthreads();
    for (int ks = 0; ks < 2; ++ks) {
      int lsl = (ks << 2) + (lane >> 4);
      int psl = lsl ^ (lane & 7);
      bf16x8 a[4], b[4];
      for (int f = 0; f < 4; ++f)
        a[f] = *reinterpret_cast<const bf16x8*>(&As[(wm * 64 + f * 16 + (lane & 15)) * 64 + psl * 8]);
      for (int f = 0; f < 4; ++f)
        b[f] = *reinterpret_cast<const bf16x8*>(&Bs[(wn * 64 + f * 16 + (lane & 15)) * 64 + psl * 8]);
      for (int fm = 0; fm < 4; ++fm)
        for (int fn = 0; fn < 4; ++fn)
          acc[fm][fn] = __builtin_amdgcn_mfma_f32_16x16x32_bf16(a[fm], b[fn], acc[fm][fn], 0, 0, 0);
    }
    __syncthreads();
  }
  for (int fm = 0; fm < 4; ++fm)
    for (int fn = 0; fn < 4; ++fn) {
      int o  = ntile * 128 + wn * 64 + fn * 16 + (lane & 15);
      float bias = b1[o];
      int n0 = mtile * 128 + wm * 64 + fm * 16 + ((lane >> 4) << 2);
      for (int j = 0; j < 4; ++j) {
        float v = acc[fm][fn][j] + bias;
        v = v > 0.0f ? v : 0.0f;
        h[(size_t)(n0 + j) * DHID + o] = (bf16_t)v;
      }
    }
}

// ---------------- K3: xw2T[o2][ord*8192+n] = sum_o h(n,o) W2[ord](o,o2)
__global__ __launch_bounds__(256) void k_gemm_xw2(
    const bf16_t* __restrict__ h,     // [8192][1024]
    const bf16_t* __restrict__ w2t,   // [3][64][1024]
    bf16_t* __restrict__ xw2t)        // [64][24576]
{
  __shared__ bf16_t As[128 * 64];
  __shared__ bf16_t Bs[64 * 64];
  int mtile = blockIdx.x, ord = blockIdx.y;
  int tid = threadIdx.x, lane = tid & 63, wid = tid >> 6;
  int wm = wid >> 1, wn = wid & 1;
  int sl = (lane & 7) ^ (lane >> 3);
  f32x4 acc[4][2] = {};
  const bf16_t* w2o = w2t + (size_t)ord * DOUT * DHID;
  for (int kt = 0; kt < DHID; kt += 64) {
    for (int j = 0; j < 4; ++j) {           // A: h rows
      int q = wid * 4 + j;
      int row = q * 8 + (lane >> 3);
      const bf16_t* g = h + (size_t)(mtile * 128 + row) * DHID + kt + sl * 8;
      GLDS(g, &As[q * 512]);
    }
    for (int j = 0; j < 2; ++j) {           // B: W2T rows (o2), 8 KB
      int q = wid * 2 + j;
      int row = q * 8 + (lane >> 3);
      const bf16_t* g = w2o + (size_t)row * DHID + kt + sl * 8;
      GLDS(g, &Bs[q * 512]);
    }
    __syncthreads();
    for (int ks = 0; ks < 2; ++ks) {
      int lsl = (ks << 2) + (lane >> 4);
      int psl = lsl ^ (lane & 7);
      bf16x8 a[4], b[2];
      for (int f = 0; f < 4; ++f)
        a[f] = *reinterpret_cast<const bf16x8*>(&As[(wm * 64 + f * 16 + (lane & 15)) * 64 + psl * 8]);
      for (int f = 0; f < 2; ++f)
        b[f] = *reinterpret_cast<const bf16x8*>(&Bs[(wn * 32 + f * 16 + (lane & 15)) * 64 + psl * 8]);
      for (int fm = 0; fm < 4; ++fm)
        for (int fn = 0; fn < 2; ++fn)
          acc[fm][fn] = __builtin_amdgcn_mfma_f32_16x16x32_bf16(a[fm], b[fn], acc[fm][fn], 0, 0, 0);
    }
    __syncthreads();
  }
  for (int fm = 0; fm < 4; ++fm)
    for (int fn = 0; fn < 2; ++fn) {
      int o2 = wn * 32 + fn * 16 + (lane & 15);
      int n0 = mtile * 128 + wm * 64 + fm * 16 + ((lane >> 4) << 2);
      bf16x4 v;
      v[0] = (bf16_t)acc[fm][fn][0]; v[1] = (bf16_t)acc[fm][fn][1];
      v[2] = (bf16_t)acc[fm][fn][2]; v[3] = (bf16_t)acc[fm][fn][3];
      *reinterpret_cast<bf16x4*>(&xw2t[(size_t)o2 * KTOT + ord * NROWS + n0]) = v;
    }
}

// ---------------- K4a: partial z = adjcat @ xw2, K split 4 ways
__global__ __launch_bounds__(256) void k_gemm_out(
    const float* __restrict__ adj,
    const bf16_t* __restrict__ xw2t,   // [64][24576]
    float* __restrict__ part)          // [4][8192][64]
{
  __shared__ bf16_t As[128 * 64];
  __shared__ bf16_t Bs[64 * 64];
  int mtile = blockIdx.x, ksp = blockIdx.y;
  int tid = threadIdx.x, lane = tid & 63, wid = tid >> 6;
  int wm = wid >> 1, wn = wid & 1;
  int sl = (lane & 7) ^ (lane >> 3);
  f32x4 acc[4][2] = {};
  for (int kt = ksp * 96; kt < ksp * 96 + 96; ++kt) {
    int kk0 = kt * 64;
    int ord = kk0 >> 13;
    int mcol = kk0 & 8191;
    for (int j = 0; j < 2; ++j) {           // B: xw2T rows (o2), pre-swizzled source
      int q = wid * 2 + j;
      int row = q * 8 + (lane >> 3);
      const bf16_t* g = xw2t + (size_t)row * KTOT + kk0 + sl * 8;
      GLDS(g, &Bs[q * 512]);
    }
    const float* abase = adj + (size_t)ord * NROWS * NROWS + (size_t)(mtile * 128) * NROWS + mcol;
    bf16x8 st[4]; int mrow[4], kb[4];
    for (int i = 0; i < 4; ++i) {
      int c = i * 256 + tid;
      mrow[i] = c >> 3; kb[i] = c & 7;
      const float4* p = reinterpret_cast<const float4*>(abase + (size_t)mrow[i] * NROWS + kb[i] * 8);
      float4 v0 = p[0], v1 = p[1];
      bf16x8 o;
      o[0]=(bf16_t)v0.x; o[1]=(bf16_t)v0.y; o[2]=(bf16_t)v0.z; o[3]=(bf16_t)v0.w;
      o[4]=(bf16_t)v1.x; o[5]=(bf16_t)v1.y; o[6]=(bf16_t)v1.z; o[7]=(bf16_t)v1.w;
      st[i] = o;
    }
    for (int i = 0; i < 4; ++i)
      *reinterpret_cast<bf16x8*>(&As[mrow[i] * 64 + (kb[i] ^ (mrow[i] & 7)) * 8]) = st[i];
    __syncthreads();
    for (int ks = 0; ks < 2; ++ks) {
      int lsl = (ks << 2) + (lane >> 4);
      int psl = lsl ^ (lane & 7);
      bf16x8 a[4], b[2];
      for (int f = 0; f < 4; ++f)
        a[f] = *reinterpret_cast<const bf16x8*>(&As[(wm * 64 + f * 16 + (lane & 15)) * 64 + psl * 8]);
      for (int f = 0; f < 2; ++f)
        b[f] = *reinterpret_cast<const bf16x8*>(&Bs[(wn * 32 + f * 16 + (lane & 15)) * 64 + psl * 8]);
      for (int fm = 0; fm < 4; ++fm)
        for (int fn = 0; fn < 2; ++fn)
          acc[fm][fn] = __builtin_amdgcn_mfma_f32_16x16x32_bf16(a[fm], b[fn], acc[fm][fn], 0, 0, 0);
    }
    __syncthreads();
  }
  float* pout = part + (size_t)ksp * NROWS * DOUT;
  for (int fm = 0; fm < 4; ++fm)
    for (int fn = 0; fn < 2; ++fn) {
      int o2 = wn * 32 + fn * 16 + (lane & 15);
      int n0 = mtile * 128 + wm * 64 + fm * 16 + ((lane >> 4) << 2);
      for (int j = 0; j < 4; ++j)
        pout[(size_t)(n0 + j) * DOUT + o2] = acc[fm][fn][j];
    }
}

// ---------------- K4b: sum partials + b2, row log_softmax ----------------
__global__ void k_logsoftmax(const float* __restrict__ part, const float* __restrict__ b2,
                             float* __restrict__ out) {
  int wid = threadIdx.x >> 6, lane = threadIdx.x & 63;
  int n = blockIdx.x * 4 + wid;
  size_t s = (size_t)NROWS * DOUT;
  float v = part[(size_t)n * DOUT + lane] + part[s + (size_t)n * DOUT + lane]
          + part[2 * s + (size_t)n * DOUT + lane] + part[3 * s + (size_t)n * DOUT + lane]
          + b2[lane];
  float mx = v;
  for (int d = 32; d; d >>= 1) mx = fmaxf(mx, __shfl_xor(mx, d));
  float e = expf(v - mx);
  float sum = e;
  for (int d = 32; d; d >>= 1) sum += __shfl_xor(sum, d);
  out[(size_t)n * DOUT + lane] = (v - mx) - logf(sum);
}

// ---------------------------------------------------------------------------
extern "C" void kernel_launch(void* const* d_in, const int* in_sizes, int n_in,
                              void* d_out, int out_size, void* d_ws, size_t ws_size,
                              hipStream_t stream) {
  const float* x   = (const float*)d_in[0];
  const float* adj = (const float*)d_in[1];
  const float* W1  = (const float*)d_in[2];
  const float* b1  = (const float*)d_in[3];
  const float* W2  = (const float*)d_in[4];
  const float* b2  = (const float*)d_in[5];
  float* out = (float*)d_out;
  char* ws = (char*)d_ws;

  bf16_t* xb   = (bf16_t*)(ws + 0);          //  8 MB  [8192][512]
  bf16_t* w1t  = (bf16_t*)(ws + 8388608);    //  3 MB  [3][1024][512]
  bf16_t* w2t  = (bf16_t*)(ws + 11534336);   //  384K  [3][64][1024]
  bf16_t* xw1t = (bf16_t*)(ws + 11927552);   // 48 MB  [1024][24576]
  bf16_t* h    = (bf16_t*)(ws + 62259200);   // 16 MB  [8192][1024]
  bf16_t* xw2t = (bf16_t*)(ws + 79036416);   //  3 MB  [64][24576]
  float*  part = (float*)(ws + 82182144);    //  8 MB  [4][8192][64]

  k_cvt_x<<<2048, 256, 0, stream>>>(x, xb);
  k_transpose_cvt<<<dim3(16, 8, 3), 256, 0, stream>>>(W1, w1t, DIN, DHID);
  k_transpose_cvt<<<dim3(1, 16, 3), 256, 0, stream>>>(W2, w2t, DHID, DOUT);
  k_gemm_xw1<<<dim3(8, 64, 3), 256, 0, stream>>>(xb, w1t, xw1t);
  k_gemm_h<<<512, 256, 0, stream>>>(adj, xw1t, b1, h);
  k_gemm_xw2<<<dim3(64, 3), 256, 0, stream>>>(h, w2t, xw2t);
  k_gemm_out<<<dim3(64, 4), 256, 0, stream>>>(adj, xw2t, part);
  k_logsoftmax<<<2048, 256, 0, stream>>>(part, b2, out);
}